// Round 9
// baseline (678.963 us; speedup 1.0000x reference)
//
#include <hip/hip_runtime.h>
#include <math.h>
#include <stdint.h>

// Problem constants (match reference)
#define FEAT   128
#define NBANK  1000000
#define KP1    4097            // K_NEG + 1
#define BATCH  256
#define INV_T  2.0f            // 1 / T, T = 0.5
#define EPS_N  1e-7f

// Output layout (floats, concatenated in return order)
constexpr size_t TOTP   = (size_t)BATCH * KP1;        // 1048832 per score output
constexpr size_t O_OUTL = 0;
constexpr size_t O_OUTA = TOTP;                       // 1048832
constexpr size_t O_MEML = 2 * TOTP;                   // 2097664
constexpr size_t O_MEMA = O_MEML + (size_t)NBANK * FEAT; // 130097664

// Per-ROW inverted index: avg entries/row = 1048832/1e6 = 1.05 (Poisson).
// CAP=16 -> P(overflow anywhere) ~ 1e-9. One 64B line per row, aligned.
constexpr int CAP    = 16;
constexpr int NTILE  = NBANK / 16;                    // 62500 row-tiles (16 rows)
constexpr int GRID_M = 2048;                          // main grid (8 blocks/CU)

// Workspace layout. Float region first, then u32 region.
constexpr size_t WS_LN   = 0;        // 256*128 floats
constexpr size_t WS_ABN  = 32768;    // 256*128 floats
constexpr size_t WS_INVZ = 65536;    // 2 floats
constexpr size_t WS_PL   = 65544;    // 256 floats (Z partials, out_l)
constexpr size_t WS_PA   = 65800;    // 256 floats (Z partials, out_ab)
constexpr size_t WS_U32  = 66560;    // u32 region starts here (float index)
// u32 region: CNT[NBANK] (4 MB), ENT[NBANK*CAP] (64 MB)

typedef float vfloat4 __attribute__((ext_vector_type(4)));

__device__ __forceinline__ float dot4(vfloat4 a, vfloat4 b) {
    return a.x * b.x + a.y * b.y + a.z * b.z + a.w * b.w;
}

// ---------------------------------------------------------------------------
// 1) L2-normalize l and ab rows + zero per-row counters (grid-stride, folded).
//    512 blocks x 64 threads.
// ---------------------------------------------------------------------------
__global__ void norm_zero_kernel(const float* __restrict__ l,
                                 const float* __restrict__ ab,
                                 float* __restrict__ ws,
                                 unsigned int* __restrict__ cnt) {
    int b    = blockIdx.x;
    int lane = threadIdx.x;           // 0..63, 2 floats per lane
    for (int i = b * 64 + lane; i < NBANK; i += 512 * 64) cnt[i] = 0u;
    const float* src;
    float*       dst;
    if (b < BATCH) { src = l  + (size_t)b * FEAT;            dst = ws + WS_LN  + (size_t)b * FEAT; }
    else           { src = ab + (size_t)(b - BATCH) * FEAT;  dst = ws + WS_ABN + (size_t)(b - BATCH) * FEAT; }
    float2 v = *(const float2*)(src + 2 * lane);
    float  ss = v.x * v.x + v.y * v.y;
    #pragma unroll
    for (int m = 1; m < 64; m <<= 1) ss += __shfl_xor(ss, m, 64);
    float inv = 1.0f / (sqrtf(ss) + EPS_N);
    ((float2*)dst)[lane] = make_float2(v.x * inv, v.y * inv);
}

// ---------------------------------------------------------------------------
// 2) Build per-row inverted index in ONE pass.
//    Entry pack: (b<<13)|k. Order within a row is arbitrary (atomic), but
//    every (b,k) gets exactly one slot -> P outputs deterministic.
// ---------------------------------------------------------------------------
__global__ void build_kernel(const int* __restrict__ idx,
                             unsigned int* __restrict__ cnt,
                             unsigned int* __restrict__ ent) {
    size_t stride = (size_t)gridDim.x * blockDim.x;
    for (size_t p = (size_t)blockIdx.x * blockDim.x + threadIdx.x; p < TOTP; p += stride) {
        int row = idx[p];
        int b   = (int)(p / KP1);
        int k   = (int)(p - (size_t)b * KP1);
        unsigned int pos = atomicAdd(&cnt[row], 1u);
        if (pos < (unsigned int)CAP)
            ent[(size_t)row * CAP + pos] = ((unsigned int)b << 13) | (unsigned int)k;
    }
}

// ---------------------------------------------------------------------------
// 3) MAIN: register-direct, barrier-free. Each 16-lane group owns ONE bank
//    row: load both banks' row into regs (coalesced 512B/group), store the
//    copy straight from regs, score the row's own entries from the SAME regs.
//    No LDS, no __syncthreads, every wave an independent stream.
// ---------------------------------------------------------------------------
__global__ __launch_bounds__(256) void main_kernel(
        const float* __restrict__ mem_l, const float* __restrict__ mem_ab,
        const float* __restrict__ ws_f,            // ln/abn tables
        const unsigned int* __restrict__ cnt,
        const unsigned int* __restrict__ ent,
        float* __restrict__ out) {
    int tid    = threadIdx.x;
    int g      = tid >> 4;            // group 0..15 -> row within tile
    int lane16 = tid & 15;            // 32B segment within row

    for (int t = blockIdx.x; t < NTILE; t += GRID_M) {
        int    row   = t * 16 + g;
        size_t rbase = (size_t)row * FEAT;

        // count first (independent load, ready by score time)
        int c = (int)cnt[row];

        // row loads: 2 vfloat4 per lane per bank (group covers 512B)
        const vfloat4* pl = (const vfloat4*)(mem_l  + rbase) + lane16 * 2;
        const vfloat4* pa = (const vfloat4*)(mem_ab + rbase) + lane16 * 2;
        vfloat4 wl0 = pl[0], wl1 = pl[1];      // memory_l row
        vfloat4 wa0 = pa[0], wa1 = pa[1];      // memory_ab row

        // copy-out straight from regs
        vfloat4* dl = (vfloat4*)(out + O_MEML + rbase) + lane16 * 2;
        vfloat4* da = (vfloat4*)(out + O_MEMA + rbase) + lane16 * 2;
        dl[0] = wl0; dl[1] = wl1;
        da[0] = wa0; da[1] = wa1;

        // score this row's entries (avg 1.05; divergence across groups is fine)
        for (int e = 0; e < c && e < CAP; ++e) {
            unsigned int ev = ent[(size_t)row * CAP + e];
            int b = (int)(ev >> 13);
            int k = (int)(ev & 0x1FFFu);
            const vfloat4* lq = (const vfloat4*)(ws_f + WS_LN  + (size_t)b * FEAT) + lane16 * 2;
            const vfloat4* aq = (const vfloat4*)(ws_f + WS_ABN + (size_t)b * FEAT) + lane16 * 2;
            vfloat4 lv0 = lq[0], lv1 = lq[1];
            vfloat4 av0 = aq[0], av1 = aq[1];
            float dlv  = dot4(wa0, lv0) + dot4(wa1, lv1);   // -> P_l
            float dabv = dot4(wl0, av0) + dot4(wl1, av1);   // -> P_ab
            #pragma unroll
            for (int m = 1; m < 16; m <<= 1) {
                dlv  += __shfl_xor(dlv,  m, 64);
                dabv += __shfl_xor(dabv, m, 64);
            }
            if (lane16 == 0) {
                out[O_OUTL + (size_t)b * KP1 + k] = __expf(dlv  * INV_T);
                out[O_OUTA + (size_t)b * KP1 + k] = __expf(dabv * INV_T);
            }
        }
    }
}

// ---------------------------------------------------------------------------
// 4a) Z partials from the completed P arrays, fixed slicing (deterministic)
// ---------------------------------------------------------------------------
__global__ void zsum_kernel(const float* __restrict__ out,
                            float* __restrict__ pl, float* __restrict__ pa) {
    __shared__ float sl[256], sa[256];
    int i = blockIdx.x, t = threadIdx.x;
    const float* bl = out + O_OUTL + (size_t)i * KP1;
    const float* ba = out + O_OUTA + (size_t)i * KP1;
    float a = 0.f, b = 0.f;
    for (int p = t; p < KP1; p += 256) { a += bl[p]; b += ba[p]; }
    sl[t] = a; sa[t] = b;
    __syncthreads();
    for (int s = 128; s > 0; s >>= 1) {
        if (t < s) { sl[t] += sl[t + s]; sa[t] += sa[t + s]; }
        __syncthreads();
    }
    if (t == 0) { pl[i] = sl[0]; pa[i] = sa[0]; }
}

// ---------------------------------------------------------------------------
// 4b) final Z -> 1/Z
// ---------------------------------------------------------------------------
__global__ void zfinal_kernel(const float* __restrict__ pl,
                              const float* __restrict__ pa,
                              float* __restrict__ invz) {
    if (threadIdx.x == 0) {
        float a = 0.f, b = 0.f;
        for (int i = 0; i < 256; ++i) { a += pl[i]; b += pa[i]; }
        float count = (float)TOTP;
        invz[0] = count / (a * (float)NBANK);
        invz[1] = count / (b * (float)NBANK);
    }
}

// ---------------------------------------------------------------------------
// 5) Scale both P regions in place by 1/Z
// ---------------------------------------------------------------------------
__global__ void scale_kernel(float* __restrict__ out, const float* __restrict__ invz) {
    float zl = invz[0], za = invz[1];
    size_t stride = (size_t)gridDim.x * blockDim.x;
    for (size_t i = (size_t)blockIdx.x * blockDim.x + threadIdx.x; i < TOTP; i += stride) {
        out[O_OUTL + i] *= zl;
        out[O_OUTA + i] *= za;
    }
}

// ---------------------------------------------------------------------------
// 6) Momentum scatter update (reads ORIGINAL banks, writes into d_out copies)
//    Last-wins on duplicate y to match numpy scatter semantics.
// ---------------------------------------------------------------------------
__global__ void update_kernel(const float* __restrict__ mem_l,
                              const float* __restrict__ mem_ab,
                              const int*   __restrict__ y,
                              const float* __restrict__ ws,
                              float* __restrict__ out) {
    int b    = blockIdx.x;
    int lane = threadIdx.x;
    int row  = y[b];
    for (int j = b + 1; j < BATCH; ++j)
        if (y[j] == row) return;              // a later write wins
    {
        float2 m = ((const float2*)(mem_l + (size_t)row * FEAT))[lane];
        float2 x = ((const float2*)(ws + WS_LN + (size_t)b * FEAT))[lane];
        float2 p = make_float2(m.x * 0.5f + x.x * 0.5f, m.y * 0.5f + x.y * 0.5f);
        float ss = p.x * p.x + p.y * p.y;
        #pragma unroll
        for (int mk = 1; mk < 64; mk <<= 1) ss += __shfl_xor(ss, mk, 64);
        float nrm = sqrtf(ss);
        ((float2*)(out + O_MEML + (size_t)row * FEAT))[lane] =
            make_float2(p.x / nrm, p.y / nrm);
    }
    {
        float2 m = ((const float2*)(mem_ab + (size_t)row * FEAT))[lane];
        float2 x = ((const float2*)(ws + WS_ABN + (size_t)b * FEAT))[lane];
        float2 p = make_float2(m.x * 0.5f + x.x * 0.5f, m.y * 0.5f + x.y * 0.5f);
        float ss = p.x * p.x + p.y * p.y;
        #pragma unroll
        for (int mk = 1; mk < 64; mk <<= 1) ss += __shfl_xor(ss, mk, 64);
        float nrm = sqrtf(ss);
        ((float2*)(out + O_MEMA + (size_t)row * FEAT))[lane] =
            make_float2(p.x / nrm, p.y / nrm);
    }
}

// ---------------------------------------------------------------------------
extern "C" void kernel_launch(void* const* d_in, const int* in_sizes, int n_in,
                              void* d_out, int out_size, void* d_ws, size_t ws_size,
                              hipStream_t stream) {
    const float* l      = (const float*)d_in[0];
    const float* ab     = (const float*)d_in[1];
    const float* mem_l  = (const float*)d_in[2];
    const float* mem_ab = (const float*)d_in[3];
    const int*   y      = (const int*)d_in[4];
    const int*   idx    = (const int*)d_in[5];
    float* out = (float*)d_out;
    float* ws  = (float*)d_ws;

    unsigned int* wsu = (unsigned int*)(ws + WS_U32);
    unsigned int* cnt = wsu;
    unsigned int* ent = wsu + NBANK;

    // 1) normalize queries + zero per-row counters
    norm_zero_kernel<<<dim3(2 * BATCH), dim3(64), 0, stream>>>(l, ab, ws, cnt);
    // 2) one-pass per-row inverted index build
    build_kernel<<<dim3(2048), dim3(256), 0, stream>>>(idx, cnt, ent);
    // 3) register-direct stream: copy-out + score from regs (no LDS/barrier)
    main_kernel<<<dim3(GRID_M), dim3(256), 0, stream>>>(
        mem_l, mem_ab, ws, cnt, ent, out);
    // 4) Z from completed P arrays (fixed order)
    zsum_kernel  <<<dim3(256), dim3(256), 0, stream>>>(out, ws + WS_PL, ws + WS_PA);
    zfinal_kernel<<<dim3(1),   dim3(64),  0, stream>>>(ws + WS_PL, ws + WS_PA, ws + WS_INVZ);
    // 5) scale P by 1/Z
    scale_kernel<<<dim3(1024), dim3(256), 0, stream>>>(out, ws + WS_INVZ);
    // 6) momentum scatter update (after copy, last-wins)
    update_kernel<<<dim3(BATCH), dim3(64), 0, stream>>>(mem_l, mem_ab, y, ws, out);
}

// Round 10
// 515.674 us; speedup vs baseline: 1.3167x; 1.3167x over previous
//
#include <hip/hip_runtime.h>
#include <math.h>
#include <stdint.h>

// Problem constants (match reference)
#define FEAT   128
#define NBANK  1000000
#define KP1    4097            // K_NEG + 1
#define BATCH  256
#define INV_T  2.0f            // 1 / T, T = 0.5
#define EPS_N  1e-7f

// Output layout (floats, concatenated in return order)
constexpr size_t TOTP   = (size_t)BATCH * KP1;        // 1048832 per score output
constexpr size_t O_OUTL = 0;
constexpr size_t O_OUTA = TOTP;                       // 1048832
constexpr size_t O_MEML = 2 * TOTP;                   // 2097664
constexpr size_t O_MEMA = O_MEML + (size_t)NBANK * FEAT; // 130097664

// Inverted-index geometry: buckets of 16 bank rows, fixed-capacity slots.
// Avg entries/bucket = 1048832/62500 = 16.8 (Poisson); CAP=128 is ~27 sigma.
constexpr int RPB   = 16;
constexpr int NBUCK = NBANK / RPB;                    // 62500 (exact)
constexpr int CAP   = 128;

// Workspace layout. Float region first, then u32 region.
constexpr size_t WS_LN   = 0;        // 256*128 floats
constexpr size_t WS_ABN  = 32768;    // 256*128 floats
constexpr size_t WS_PL   = 65544;    // 256 floats (Z partials, out_l)
constexpr size_t WS_PA   = 65800;    // 256 floats (Z partials, out_ab)
constexpr size_t WS_U32  = 66560;    // u32 region starts here (float index)
// u32 region: CNT[NBUCK], ENT[NBUCK*CAP]  (~32.3 MB total; ws is ~4 GB)

typedef float vfloat4 __attribute__((ext_vector_type(4)));

__device__ __forceinline__ float dot4(vfloat4 a, vfloat4 b) {
    return a.x * b.x + a.y * b.y + a.z * b.z + a.w * b.w;
}

// ---------------------------------------------------------------------------
// 1) L2-normalize l and ab rows + zero bucket counters (grid-stride, folded).
//    512 blocks x 64 threads.
// ---------------------------------------------------------------------------
__global__ void norm_zero_kernel(const float* __restrict__ l,
                                 const float* __restrict__ ab,
                                 float* __restrict__ ws,
                                 unsigned int* __restrict__ cnt) {
    int b    = blockIdx.x;
    int lane = threadIdx.x;           // 0..63, 2 floats per lane
    for (int i = b * 64 + lane; i < NBUCK; i += 512 * 64) cnt[i] = 0u;
    const float* src;
    float*       dst;
    if (b < BATCH) { src = l  + (size_t)b * FEAT;            dst = ws + WS_LN  + (size_t)b * FEAT; }
    else           { src = ab + (size_t)(b - BATCH) * FEAT;  dst = ws + WS_ABN + (size_t)(b - BATCH) * FEAT; }
    float2 v = *(const float2*)(src + 2 * lane);
    float  ss = v.x * v.x + v.y * v.y;
    #pragma unroll
    for (int m = 1; m < 64; m <<= 1) ss += __shfl_xor(ss, m, 64);
    float inv = 1.0f / (sqrtf(ss) + EPS_N);
    ((float2*)dst)[lane] = make_float2(v.x * inv, v.y * inv);
}

// ---------------------------------------------------------------------------
// 2) Build inverted index in ONE pass: fixed-capacity buckets.
//    Entry pack: (b<<17)|(k<<4)|(row&15). Order within bucket is arbitrary
//    (atomic), but every (b,k) gets exactly one slot -> P deterministic.
// ---------------------------------------------------------------------------
__global__ void build_kernel(const int* __restrict__ idx,
                             unsigned int* __restrict__ cnt,
                             unsigned int* __restrict__ ent) {
    size_t stride = (size_t)gridDim.x * blockDim.x;
    for (size_t p = (size_t)blockIdx.x * blockDim.x + threadIdx.x; p < TOTP; p += stride) {
        int row = idx[p];
        int b   = (int)(p / KP1);
        int k   = (int)(p - (size_t)b * KP1);
        int bucket = row >> 4;
        unsigned int pos = atomicAdd(&cnt[bucket], 1u);
        if (pos < (unsigned int)CAP)
            ent[(size_t)bucket * CAP + pos] =
                ((unsigned int)b << 17) | ((unsigned int)k << 4) | (unsigned int)(row & 15);
    }
}

// ---------------------------------------------------------------------------
// 3) COPY+SCORE, one bank per launch: a clean 2-stream copy (1 read + 1
//    write of 8 KB/block) plus scoring of this window's entries against the
//    query table. Score row reads re-touch the just-loaded lines -> L1 hits.
//    No LDS, no barrier. Block-per-tile grid keeps dispatch-order locality.
//      bank = mem_l : qtab = abn, pout = out_ab region
//      bank = mem_ab: qtab = ln,  pout = out_l  region
// ---------------------------------------------------------------------------
__global__ __launch_bounds__(256) void copyscore_kernel(
        const float* __restrict__ src, float* __restrict__ dst,
        const float* __restrict__ qtab, float* __restrict__ pout,
        const unsigned int* __restrict__ cnt,
        const unsigned int* __restrict__ ent) {
    int blk = blockIdx.x;                // 0..NBUCK-1
    int tid = threadIdx.x;
    size_t fbase = (size_t)blk * RPB * FEAT;       // float offset of window

    // entry count first (scalar, overlaps with bank loads)
    int c = min((int)cnt[blk], CAP);

    // copy: 2 vfloat4 per thread (8 KB window)
    const vfloat4* s = (const vfloat4*)(src + fbase);
    vfloat4 v0 = s[tid], v1 = s[256 + tid];
    vfloat4* d = (vfloat4*)(dst + fbase);
    d[tid] = v0; d[256 + tid] = v1;

    // score window entries; rows from global (L1-resident), queries via L2
    int g = tid >> 4, lane16 = tid & 15;           // 16 groups of 16 lanes
    for (int i = g; i < c; i += 16) {
        unsigned int ev = ent[(size_t)blk * CAP + i];
        int rloc = (int)(ev & 15u);
        int k    = (int)((ev >> 4) & 0x1FFFu);
        int b    = (int)(ev >> 17);
        const vfloat4* rp = (const vfloat4*)(src + fbase + (size_t)rloc * FEAT) + lane16 * 2;
        vfloat4 w0 = rp[0], w1 = rp[1];
        const vfloat4* qp = (const vfloat4*)(qtab + (size_t)b * FEAT) + lane16 * 2;
        vfloat4 q0 = qp[0], q1 = qp[1];
        float dv = dot4(w0, q0) + dot4(w1, q1);
        #pragma unroll
        for (int m = 1; m < 16; m <<= 1) dv += __shfl_xor(dv, m, 64);
        if (lane16 == 0) pout[(size_t)b * KP1 + k] = __expf(dv * INV_T);
    }
}

// ---------------------------------------------------------------------------
// 4) Z partials from the completed P arrays, fixed slicing (deterministic)
// ---------------------------------------------------------------------------
__global__ void zsum_kernel(const float* __restrict__ out,
                            float* __restrict__ pl, float* __restrict__ pa) {
    __shared__ float sl[256], sa[256];
    int i = blockIdx.x, t = threadIdx.x;
    const float* bl = out + O_OUTL + (size_t)i * KP1;
    const float* ba = out + O_OUTA + (size_t)i * KP1;
    float a = 0.f, b = 0.f;
    for (int p = t; p < KP1; p += 256) { a += bl[p]; b += ba[p]; }
    sl[t] = a; sa[t] = b;
    __syncthreads();
    for (int s = 128; s > 0; s >>= 1) {
        if (t < s) { sl[t] += sl[t + s]; sa[t] += sa[t + s]; }
        __syncthreads();
    }
    if (t == 0) { pl[i] = sl[0]; pa[i] = sa[0]; }
}

// ---------------------------------------------------------------------------
// 5) Fused: finalize Z (every block, deterministic fixed order) + scale this
//    block's P slices + momentum-update this block's batch row (last-wins).
//    grid: 256 blocks x 256 threads; block b owns batch row b.
// ---------------------------------------------------------------------------
__global__ void finish_kernel(const float* __restrict__ pl,
                              const float* __restrict__ pa,
                              const float* __restrict__ mem_l,
                              const float* __restrict__ mem_ab,
                              const int*   __restrict__ y,
                              const float* __restrict__ ws,
                              float* __restrict__ out) {
    __shared__ float s2[2];
    int b = blockIdx.x, t = threadIdx.x;
    if (t == 0) {
        float a = 0.f, c = 0.f;
        for (int i = 0; i < 256; ++i) { a += pl[i]; c += pa[i]; }
        float count = (float)TOTP;
        s2[0] = count / (a * (float)NBANK);
        s2[1] = count / (c * (float)NBANK);
    }
    __syncthreads();
    float zl = s2[0], za = s2[1];
    float* bl = out + O_OUTL + (size_t)b * KP1;
    float* ba = out + O_OUTA + (size_t)b * KP1;
    for (int p = t; p < KP1; p += 256) { bl[p] *= zl; ba[p] *= za; }

    // momentum scatter update (threads 0..63), last-wins on duplicate y
    if (t < 64) {
        int lane = t;
        int row  = y[b];
        bool win = true;
        for (int j = b + 1; j < BATCH; ++j)
            if (y[j] == row) { win = false; break; }
        if (win) {
            {
                float2 m = ((const float2*)(mem_l + (size_t)row * FEAT))[lane];
                float2 x = ((const float2*)(ws + WS_LN + (size_t)b * FEAT))[lane];
                float2 p = make_float2(m.x * 0.5f + x.x * 0.5f, m.y * 0.5f + x.y * 0.5f);
                float ss = p.x * p.x + p.y * p.y;
                #pragma unroll
                for (int mk = 1; mk < 64; mk <<= 1) ss += __shfl_xor(ss, mk, 64);
                float nrm = sqrtf(ss);
                ((float2*)(out + O_MEML + (size_t)row * FEAT))[lane] =
                    make_float2(p.x / nrm, p.y / nrm);
            }
            {
                float2 m = ((const float2*)(mem_ab + (size_t)row * FEAT))[lane];
                float2 x = ((const float2*)(ws + WS_ABN + (size_t)b * FEAT))[lane];
                float2 p = make_float2(m.x * 0.5f + x.x * 0.5f, m.y * 0.5f + x.y * 0.5f);
                float ss = p.x * p.x + p.y * p.y;
                #pragma unroll
                for (int mk = 1; mk < 64; mk <<= 1) ss += __shfl_xor(ss, mk, 64);
                float nrm = sqrtf(ss);
                ((float2*)(out + O_MEMA + (size_t)row * FEAT))[lane] =
                    make_float2(p.x / nrm, p.y / nrm);
            }
        }
    }
}

// ---------------------------------------------------------------------------
extern "C" void kernel_launch(void* const* d_in, const int* in_sizes, int n_in,
                              void* d_out, int out_size, void* d_ws, size_t ws_size,
                              hipStream_t stream) {
    const float* l      = (const float*)d_in[0];
    const float* ab     = (const float*)d_in[1];
    const float* mem_l  = (const float*)d_in[2];
    const float* mem_ab = (const float*)d_in[3];
    const int*   y      = (const int*)d_in[4];
    const int*   idx    = (const int*)d_in[5];
    float* out = (float*)d_out;
    float* ws  = (float*)d_ws;

    unsigned int* wsu = (unsigned int*)(ws + WS_U32);
    unsigned int* cnt = wsu;
    unsigned int* ent = wsu + NBUCK;

    // 1) normalize queries + zero bucket counters
    norm_zero_kernel<<<dim3(2 * BATCH), dim3(64), 0, stream>>>(l, ab, ws, cnt);
    // 2) one-pass inverted index build (fixed-capacity buckets)
    build_kernel<<<dim3(2048), dim3(256), 0, stream>>>(idx, cnt, ent);
    // 3) two clean 2-stream copy+score kernels, one per bank
    //    bank L -> scores P_ab (mem_l rows . abn)
    copyscore_kernel<<<dim3(NBUCK), dim3(256), 0, stream>>>(
        mem_l, out + O_MEML, ws + WS_ABN, out + O_OUTA, cnt, ent);
    //    bank AB -> scores P_l (mem_ab rows . ln)
    copyscore_kernel<<<dim3(NBUCK), dim3(256), 0, stream>>>(
        mem_ab, out + O_MEMA, ws + WS_LN, out + O_OUTL, cnt, ent);
    // 4) Z partials (deterministic fixed slicing)
    zsum_kernel<<<dim3(256), dim3(256), 0, stream>>>(out, ws + WS_PL, ws + WS_PA);
    // 5) finalize Z + scale + momentum update (fused)
    finish_kernel<<<dim3(BATCH), dim3(256), 0, stream>>>(
        ws + WS_PL, ws + WS_PA, mem_l, mem_ab, y, ws, out);
}